// Round 1
// baseline (57.217 us; speedup 1.0000x reference)
//
#include <hip/hip_runtime.h>
#include <hip/hip_bf16.h>

// Problem constants
#define B_    64
#define C_    1280
#define HW_   49
#define A_    40
#define BN    128          // d-tile per block
#define BK    32           // k-step
#define NK    (C_/BK)      // 40
#define NTILE (C_/BN)      // 10
#define WLDS_STRIDE 40     // bf16 elems per row of w_lds (32 + 8 pad, keeps 16B align)

typedef short bf16x8 __attribute__((ext_vector_type(8)));
typedef short bf16x4 __attribute__((ext_vector_type(4)));
typedef float f32x4  __attribute__((ext_vector_type(4)));

__device__ __forceinline__ float hswish(float x) {
    float t = fminf(fmaxf(x + 3.0f, 0.0f), 6.0f);
    return x * t * (1.0f / 6.0f);
}

__device__ __forceinline__ short f2bf(float f) {
    // round-to-nearest-even bf16; compiler lowers to v_cvt_pk_bf16_f32 pairs
    __hip_bfloat16 h = __float2bfloat16(f);
    return __builtin_bit_cast(short, h);
}

// Kernel 1: adaptive avg pool (7x7) + h_swish + cvt to bf16
__global__ __launch_bounds__(256) void pool_kernel(const float* __restrict__ x,
                                                   __hip_bfloat16* __restrict__ p) {
    int t = blockIdx.x * 256 + threadIdx.x;   // [0, B_*C_), exact
    const float* src = x + (size_t)t * HW_;
    float s = 0.f;
    #pragma unroll
    for (int i = 0; i < HW_; ++i) s += src[i];
    s *= (1.0f / 49.0f);
    p[t] = __float2bfloat16(hswish(s));
}

// Kernel 2: per-(attr, d-tile) block: h = hswish(p @ W1[a] + b1[a]); partial = h . W2[a]
__global__ __launch_bounds__(256) void head_kernel(
    const short* __restrict__ p,     // [64][1280] bf16
    const float* __restrict__ W1,    // [40][1280][1280]
    const float* __restrict__ b1,    // [40][1280]
    const float* __restrict__ W2,    // [40][1280]
    float* __restrict__ part)        // [NTILE][64][40]
{
    __shared__ short w_lds[BN * WLDS_STRIDE];  // transposed tile: [d][k], bf16
    __shared__ short p_lds[B_ * BK];           // [b][k], bf16

    const int tid  = threadIdx.x;
    const int lane = tid & 63;
    const int wid  = tid >> 6;
    const int ntile = blockIdx.x;              // 0..9
    const int a     = blockIdx.y;              // 0..39
    const int n0    = ntile * BN;

    const int l15 = lane & 15;
    const int lg  = lane >> 4;

    // W1 staging map: thread covers d = tid&127, c-group = tid>>7 (16 c's, 4 per iter)
    const int sd  = tid & 127;
    const int scg = (tid >> 7) * 16;
    const float* w1base = W1 + (size_t)a * C_ * C_ + n0 + sd;

    // p staging map: row = tid>>2, k-offset = (tid&3)*8  (16B per thread)
    const int prow = tid >> 2;
    const int pkof = (tid & 3) * 8;

    f32x4 acc[8];
    #pragma unroll
    for (int n = 0; n < 8; ++n) acc[n] = (f32x4){0.f, 0.f, 0.f, 0.f};

    float  wcur[16];
    bf16x8 pcur;
    // prologue: issue loads for k-tile 0
    {
        #pragma unroll
        for (int i = 0; i < 4; ++i) {
            int cb = scg + i * 4;
            #pragma unroll
            for (int j = 0; j < 4; ++j)
                wcur[i * 4 + j] = w1base[(size_t)(cb + j) * C_];
        }
        pcur = *reinterpret_cast<const bf16x8*>(p + prow * C_ + pkof);
    }

    for (int kt = 0; kt < NK; ++kt) {
        __syncthreads();   // previous compute phase done reading LDS

        // transpose-write current tile: bf16 [d][k]
        #pragma unroll
        for (int i = 0; i < 4; ++i) {
            int cb = scg + i * 4;
            bf16x4 v;
            v[0] = f2bf(wcur[i * 4 + 0]);
            v[1] = f2bf(wcur[i * 4 + 1]);
            v[2] = f2bf(wcur[i * 4 + 2]);
            v[3] = f2bf(wcur[i * 4 + 3]);
            *reinterpret_cast<bf16x4*>(&w_lds[sd * WLDS_STRIDE + cb]) = v;  // 8B write
        }
        *reinterpret_cast<bf16x8*>(&p_lds[prow * BK + pkof]) = pcur;

        __syncthreads();

        // issue-early prefetch of next k-tile (flies under MFMA phase + next barrier)
        float  wnxt[16];
        bf16x8 pnxt;
        if (kt + 1 < NK) {
            int k0n = (kt + 1) * BK;
            const float* wb = w1base + (size_t)k0n * C_;
            #pragma unroll
            for (int i = 0; i < 4; ++i) {
                int cb = scg + i * 4;
                #pragma unroll
                for (int j = 0; j < 4; ++j)
                    wnxt[i * 4 + j] = wb[(size_t)(cb + j) * C_];
            }
            pnxt = *reinterpret_cast<const bf16x8*>(p + prow * C_ + k0n + pkof);
        }

        // compute: wave wid owns rows [wid*16, wid*16+16)
        bf16x8 afrag = *reinterpret_cast<const bf16x8*>(&p_lds[(wid * 16 + l15) * BK + lg * 8]);
        #pragma unroll
        for (int n = 0; n < 8; ++n) {
            bf16x8 bfrag = *reinterpret_cast<const bf16x8*>(
                &w_lds[(n * 16 + l15) * WLDS_STRIDE + lg * 8]);
            acc[n] = __builtin_amdgcn_mfma_f32_16x16x32_bf16(afrag, bfrag, acc[n], 0, 0, 0);
        }

        #pragma unroll
        for (int i = 0; i < 16; ++i) wcur[i] = wnxt[i];
        pcur = pnxt;
    }

    // epilogue: h_swish(acc + b1) . W2, reduce over d within block
    float partial[4] = {0.f, 0.f, 0.f, 0.f};
    #pragma unroll
    for (int n = 0; n < 8; ++n) {
        int d = n0 + n * 16 + l15;
        float b1v = b1[a * C_ + d];
        float w2v = W2[a * C_ + d];
        #pragma unroll
        for (int r = 0; r < 4; ++r) {
            float h = hswish(acc[n][r] + b1v);
            partial[r] += h * w2v;
        }
    }
    // reduce over the 16 lanes (l15) of each quarter-wave
    #pragma unroll
    for (int off = 8; off >= 1; off >>= 1) {
        #pragma unroll
        for (int r = 0; r < 4; ++r)
            partial[r] += __shfl_xor(partial[r], off, 64);
    }
    if (l15 == 0) {
        int brow = wid * 16 + lg * 4;   // C/D layout: row=(lane>>4)*4+r, col=lane&15
        #pragma unroll
        for (int r = 0; r < 4; ++r)
            part[ntile * (B_ * A_) + (brow + r) * A_ + a] = partial[r];
    }
}

// Kernel 3: sum partials over the 10 d-tiles, add b2, sigmoid
__global__ __launch_bounds__(256) void fin_kernel(const float* __restrict__ part,
                                                  const float* __restrict__ b2,
                                                  float* __restrict__ out) {
    int idx = blockIdx.x * 256 + threadIdx.x;
    if (idx >= B_ * A_) return;
    int a = idx % A_;
    float s = b2[a];
    #pragma unroll
    for (int nb = 0; nb < NTILE; ++nb) s += part[nb * (B_ * A_) + idx];
    out[idx] = 1.0f / (1.0f + expf(-s));
}

extern "C" void kernel_launch(void* const* d_in, const int* in_sizes, int n_in,
                              void* d_out, int out_size, void* d_ws, size_t ws_size,
                              hipStream_t stream) {
    const float* x  = (const float*)d_in[0];
    const float* W1 = (const float*)d_in[1];
    const float* b1 = (const float*)d_in[2];
    const float* W2 = (const float*)d_in[3];
    const float* b2 = (const float*)d_in[4];
    float* out = (float*)d_out;

    __hip_bfloat16* p = (__hip_bfloat16*)d_ws;                      // 64*1280*2 = 160 KB
    float* part = (float*)((char*)d_ws + (size_t)B_ * C_ * 2);      // 10*64*40*4 = 100 KB

    pool_kernel<<<(B_ * C_) / 256, 256, 0, stream>>>(x, p);
    head_kernel<<<dim3(NTILE, A_), 256, 0, stream>>>((const short*)p, W1, b1, W2, part);
    fin_kernel<<<(B_ * A_ + 255) / 256, 256, 0, stream>>>(part, b2, out);
}